// Round 2
// baseline (1393.782 us; speedup 1.0000x reference)
//
#include <hip/hip_runtime.h>
#include <hip/hip_bf16.h>

// BitLinearLRLS: y[b,s,o] = (sum_i x[b,s,i] * ternary(w[o,i])) * scale_eff[o]
// scale_eff = scale + A @ (B @ mean(x, axes=(0,1)))
// M = B*S = 16384, N = OUT = 4096, K = IN = 4096.

typedef __bf16 bf16x8 __attribute__((ext_vector_type(8)));
typedef float f32x4 __attribute__((ext_vector_type(4)));

#define AS1 __attribute__((address_space(1)))
#define AS3 __attribute__((address_space(3)))

static __device__ __forceinline__ unsigned short f2bf(float f) {
  // round-to-nearest-even f32 -> bf16 (inputs are finite normals)
  unsigned u = __float_as_uint(f);
  return (unsigned short)((u + 0x7FFFu + ((u >> 16) & 1u)) >> 16);
}

// ---- K1: x f32 -> bf16 copy + per-block column partial sums (512 blocks x 32 rows) ----
__global__ __launch_bounds__(256) void k_convert_reduce(
    const float* __restrict__ x, unsigned short* __restrict__ xb,
    float* __restrict__ partials) {
  const int t = threadIdx.x;
  const int b = blockIdx.x;
  const size_t row0 = (size_t)b * 32;
  float acc[16];
#pragma unroll
  for (int i = 0; i < 16; ++i) acc[i] = 0.f;
  for (int r = 0; r < 32; ++r) {
    const float4* xr = (const float4*)(x + (row0 + r) * 4096);
    ushort4* xbr = (ushort4*)(xb + (row0 + r) * 4096);
#pragma unroll
    for (int p = 0; p < 4; ++p) {
      float4 v = xr[p * 256 + t];
      ushort4 o;
      o.x = f2bf(v.x); o.y = f2bf(v.y); o.z = f2bf(v.z); o.w = f2bf(v.w);
      xbr[p * 256 + t] = o;
      acc[p * 4 + 0] += v.x; acc[p * 4 + 1] += v.y;
      acc[p * 4 + 2] += v.z; acc[p * 4 + 3] += v.w;
    }
  }
  float4* pr = (float4*)(partials + (size_t)b * 4096);
#pragma unroll
  for (int p = 0; p < 4; ++p)
    pr[p * 256 + t] = make_float4(acc[p * 4 + 0], acc[p * 4 + 1],
                                  acc[p * 4 + 2], acc[p * 4 + 3]);
}

// ---- K2: reduce 512 partial rows -> 4 partial rows ----
__global__ __launch_bounds__(256) void k_reduce2(
    const float* __restrict__ partials, float* __restrict__ p2) {
  const int cg = blockIdx.x & 15, bg = blockIdx.x >> 4;
  const int c = cg * 256 + threadIdx.x;
  float s = 0.f;
  for (int b = bg * 128; b < (bg + 1) * 128; ++b)
    s += partials[(size_t)b * 4096 + c];
  p2[bg * 4096 + c] = s;
}

// ---- K3: tmp[r] = sum_c lrls_B[r,c] * xsum[c]  (16 blocks, one per r) ----
__global__ __launch_bounds__(256) void k_tmp(
    const float* __restrict__ Bm, const float* __restrict__ p2,
    float* __restrict__ tmp) {
  const int r = blockIdx.x, t = threadIdx.x;
  float s = 0.f;
  for (int c = t; c < 4096; c += 256) {
    float xs = p2[c] + p2[4096 + c] + p2[8192 + c] + p2[12288 + c];
    s += Bm[r * 4096 + c] * xs;
  }
#pragma unroll
  for (int off = 32; off > 0; off >>= 1) s += __shfl_down(s, off, 64);
  __shared__ float red[4];
  if ((t & 63) == 0) red[t >> 6] = s;
  __syncthreads();
  if (t == 0) tmp[r] = red[0] + red[1] + red[2] + red[3];
}

// ---- K4: scale_eff[o] = scale[o] + (A[o,:] . tmp) / 16384 ----
__global__ __launch_bounds__(256) void k_scale(
    const float* __restrict__ A, const float* __restrict__ scale,
    const float* __restrict__ tmp, float* __restrict__ se) {
  const int o = blockIdx.x * 256 + threadIdx.x;
  float s = 0.f;
#pragma unroll
  for (int rr = 0; rr < 16; ++rr) s += A[o * 16 + rr] * tmp[rr];
  se[o] = scale[o] + s * (1.0f / 16384.0f);
}

// ---- K5: weight -> ternary bf16 (exact) ----
__global__ __launch_bounds__(256) void k_quant(
    const float* __restrict__ w, unsigned short* __restrict__ wq) {
  const size_t i = (size_t)blockIdx.x * 256 + threadIdx.x;
  const float4 v = ((const float4*)w)[i];
  ushort4 o;
  o.x = f2bf(fminf(1.f, fmaxf(-1.f, rintf(v.x * 2.f))));
  o.y = f2bf(fminf(1.f, fmaxf(-1.f, rintf(v.y * 2.f))));
  o.z = f2bf(fminf(1.f, fmaxf(-1.f, rintf(v.z * 2.f))));
  o.w = f2bf(fminf(1.f, fmaxf(-1.f, rintf(v.w * 2.f))));
  ((ushort4*)wq)[i] = o;
}

// ---- K6: bf16 GEMM, 128x128 tile, BK=32, 4 waves (2x2), 16x16x32 MFMA ----
// A = xb [16384][4096] bf16 row-major (K-contig); B = wq [4096][4096] bf16 (K-contig).
// Epilogue: out = acc * scale_eff[col] in f32.
__global__ __launch_bounds__(256) void k_gemm(
    const unsigned short* __restrict__ xb, const unsigned short* __restrict__ wq,
    const float* __restrict__ se, float* __restrict__ out) {
  __shared__ alignas(16) unsigned short smA[128 * 32];
  __shared__ alignas(16) unsigned short smB[128 * 32];
  const int t = threadIdx.x;
  const int lane = t & 63;
  const int wave = t >> 6;

  // bijective XCD-aware swizzle: nwg = 4096, divisible by 8
  const int bid = blockIdx.x;
  const int swz = (bid & 7) * 512 + (bid >> 3);
  const int bm = swz >> 5;  // 0..127 (M blocks of 128)
  const int bn = swz & 31;  // 0..31  (N blocks of 128)
  const size_t arow0 = (size_t)bm * 128;
  const size_t bcol0 = (size_t)bn * 128;
  const int wm = wave >> 1, wn = wave & 1;

  f32x4 acc[4][4] = {};

  // staging: thread t loads 16B; round r covers tile rows r*64 .. r*64+63
  // LDS linear [row][32 bf16]: byte = row*64 + colbyte; thread t -> row=t/4, colbyte=(t&3)*16
  const int srow = t >> 2;
  const int scol = (t & 3) * 16;
  const char* gA = (const char*)(xb + arow0 * 4096) + (size_t)srow * 8192 + scol;
  const char* gB = (const char*)(wq + bcol0 * 4096) + (size_t)srow * 8192 + scol;
  AS3 char* ldsA = (AS3 char*)smA + wave * 1024;  // HW adds lane*16
  AS3 char* ldsB = (AS3 char*)smB + wave * 1024;

  const bf16x8* lA = (const bf16x8*)smA;
  const bf16x8* lB = (const bf16x8*)smB;
  // fragment read: row = w*64 + frag*16 + (lane&15); k-halfword group = (lane>>4)*8
  const int afr = (wm * 64 + (lane & 15)) * 4 + (lane >> 4);
  const int bfr = (wn * 64 + (lane & 15)) * 4 + (lane >> 4);

  for (int k0 = 0; k0 < 4096; k0 += 32) {
    __syncthreads();  // previous iteration done reading LDS
    const size_t kb = (size_t)k0 * 2;
    __builtin_amdgcn_global_load_lds((const AS1 void*)(gA + kb),
                                     (AS3 void*)(ldsA), 16, 0, 0);
    __builtin_amdgcn_global_load_lds((const AS1 void*)(gA + kb + 64 * 8192),
                                     (AS3 void*)(ldsA + 4096), 16, 0, 0);
    __builtin_amdgcn_global_load_lds((const AS1 void*)(gB + kb),
                                     (AS3 void*)(ldsB), 16, 0, 0);
    __builtin_amdgcn_global_load_lds((const AS1 void*)(gB + kb + 64 * 8192),
                                     (AS3 void*)(ldsB + 4096), 16, 0, 0);
    __syncthreads();  // loads drained (compiler emits vmcnt(0) before barrier)

    bf16x8 af[4], bf_[4];
#pragma unroll
    for (int i = 0; i < 4; ++i) af[i] = lA[afr + i * 64];
#pragma unroll
    for (int i = 0; i < 4; ++i) bf_[i] = lB[bfr + i * 64];
#pragma unroll
    for (int mi = 0; mi < 4; ++mi)
#pragma unroll
      for (int ni = 0; ni < 4; ++ni)
        acc[mi][ni] = __builtin_amdgcn_mfma_f32_16x16x32_bf16(
            af[mi], bf_[ni], acc[mi][ni], 0, 0, 0);
  }

  // epilogue: C/D layout col = lane&15, row = (lane>>4)*4 + reg  [m89/m91]
  const int r0 = (lane >> 4) * 4;
  const int cc = lane & 15;
#pragma unroll
  for (int ni = 0; ni < 4; ++ni) {
    const size_t col = bcol0 + wn * 64 + ni * 16 + cc;
    const float sev = se[col];
#pragma unroll
    for (int mi = 0; mi < 4; ++mi) {
      const size_t row = arow0 + wm * 64 + mi * 16 + r0;
#pragma unroll
      for (int j = 0; j < 4; ++j)
        out[(row + j) * 4096 + col] = acc[mi][ni][j] * sev;
    }
  }
}

extern "C" void kernel_launch(void* const* d_in, const int* in_sizes, int n_in,
                              void* d_out, int out_size, void* d_ws, size_t ws_size,
                              hipStream_t stream) {
  const float* x     = (const float*)d_in[0];  // [4,4096,4096]
  const float* w     = (const float*)d_in[1];  // [4096,4096]
  // d_in[2] = threshold (unused: reference uses compile-time THRESH=0.5)
  const float* scale = (const float*)d_in[3];  // [4096]
  const float* lrA   = (const float*)d_in[4];  // [4096,16]
  const float* lrB   = (const float*)d_in[5];  // [16,4096]
  float* out = (float*)d_out;

  char* ws = (char*)d_ws;
  unsigned short* xb  = (unsigned short*)ws;                    // 134217728 B
  unsigned short* wq  = (unsigned short*)(ws + 134217728);      //  33554432 B
  float* partials     = (float*)(ws + 167772160);               //   8388608 B
  float* partial2     = (float*)(ws + 176160768);               //     65536 B
  float* tmp          = (float*)(ws + 176226304);               //        64 B
  float* se           = (float*)(ws + 176226368);               //     16384 B

  k_convert_reduce<<<512, 256, 0, stream>>>(x, xb, partials);
  k_reduce2<<<64, 256, 0, stream>>>(partials, partial2);
  k_tmp<<<16, 256, 0, stream>>>(lrB, partial2, tmp);
  k_scale<<<16, 256, 0, stream>>>(lrA, scale, tmp, se);
  k_quant<<<16384, 256, 0, stream>>>(w, wq);
  k_gemm<<<4096, 256, 0, stream>>>(xb, wq, se, out);
}

// Round 4
// 988.816 us; speedup vs baseline: 1.4095x; 1.4095x over previous
//
#include <hip/hip_runtime.h>
#include <hip/hip_bf16.h>

// BitLinearLRLS: y[b,s,o] = (sum_i x[b,s,i] * ternary(w[o,i])) * scale_eff[o]
// M = B*S = 16384, N = OUT = 4096, K = IN = 4096.

typedef __bf16 bf16x8 __attribute__((ext_vector_type(8)));
typedef float f32x4 __attribute__((ext_vector_type(4)));

#define AS1 __attribute__((address_space(1)))
#define AS3 __attribute__((address_space(3)))

static __device__ __forceinline__ unsigned short f2bf(float f) {
  unsigned u = __float_as_uint(f);
  return (unsigned short)((u + 0x7FFFu + ((u >> 16) & 1u)) >> 16);
}

// ---- K1: x f32 -> bf16 copy + per-block column partial sums ----
__global__ __launch_bounds__(256) void k_convert_reduce(
    const float* __restrict__ x, unsigned short* __restrict__ xb,
    float* __restrict__ partials) {
  const int t = threadIdx.x;
  const int b = blockIdx.x;
  const size_t row0 = (size_t)b * 32;
  float acc[16];
#pragma unroll
  for (int i = 0; i < 16; ++i) acc[i] = 0.f;
  for (int r = 0; r < 32; ++r) {
    const float4* xr = (const float4*)(x + (row0 + r) * 4096);
    ushort4* xbr = (ushort4*)(xb + (row0 + r) * 4096);
#pragma unroll
    for (int p = 0; p < 4; ++p) {
      float4 v = xr[p * 256 + t];
      ushort4 o;
      o.x = f2bf(v.x); o.y = f2bf(v.y); o.z = f2bf(v.z); o.w = f2bf(v.w);
      xbr[p * 256 + t] = o;
      acc[p * 4 + 0] += v.x; acc[p * 4 + 1] += v.y;
      acc[p * 4 + 2] += v.z; acc[p * 4 + 3] += v.w;
    }
  }
  float4* pr = (float4*)(partials + (size_t)b * 4096);
#pragma unroll
  for (int p = 0; p < 4; ++p)
    pr[p * 256 + t] = make_float4(acc[p * 4 + 0], acc[p * 4 + 1],
                                  acc[p * 4 + 2], acc[p * 4 + 3]);
}

__global__ __launch_bounds__(256) void k_reduce2(
    const float* __restrict__ partials, float* __restrict__ p2) {
  const int cg = blockIdx.x & 15, bg = blockIdx.x >> 4;
  const int c = cg * 256 + threadIdx.x;
  float s = 0.f;
  for (int b = bg * 128; b < (bg + 1) * 128; ++b)
    s += partials[(size_t)b * 4096 + c];
  p2[bg * 4096 + c] = s;
}

__global__ __launch_bounds__(256) void k_tmp(
    const float* __restrict__ Bm, const float* __restrict__ p2,
    float* __restrict__ tmp) {
  const int r = blockIdx.x, t = threadIdx.x;
  float s = 0.f;
  for (int c = t; c < 4096; c += 256) {
    float xs = p2[c] + p2[4096 + c] + p2[8192 + c] + p2[12288 + c];
    s += Bm[r * 4096 + c] * xs;
  }
#pragma unroll
  for (int off = 32; off > 0; off >>= 1) s += __shfl_down(s, off, 64);
  __shared__ float red[4];
  if ((t & 63) == 0) red[t >> 6] = s;
  __syncthreads();
  if (t == 0) tmp[r] = red[0] + red[1] + red[2] + red[3];
}

__global__ __launch_bounds__(256) void k_scale(
    const float* __restrict__ A, const float* __restrict__ scale,
    const float* __restrict__ tmp, float* __restrict__ se) {
  const int o = blockIdx.x * 256 + threadIdx.x;
  float s = 0.f;
#pragma unroll
  for (int rr = 0; rr < 16; ++rr) s += A[o * 16 + rr] * tmp[rr];
  se[o] = scale[o] + s * (1.0f / 16384.0f);
}

__global__ __launch_bounds__(256) void k_quant(
    const float* __restrict__ w, unsigned short* __restrict__ wq) {
  const size_t i = (size_t)blockIdx.x * 256 + threadIdx.x;
  const float4 v = ((const float4*)w)[i];
  ushort4 o;
  o.x = f2bf(fminf(1.f, fmaxf(-1.f, rintf(v.x * 2.f))));
  o.y = f2bf(fminf(1.f, fmaxf(-1.f, rintf(v.y * 2.f))));
  o.z = f2bf(fminf(1.f, fmaxf(-1.f, rintf(v.z * 2.f))));
  o.w = f2bf(fminf(1.f, fmaxf(-1.f, rintf(v.w * 2.f))));
  ((ushort4*)wq)[i] = o;
}

// ---- K6: 256x256 8-phase bf16 GEMM (m201-style template) ----
// BM=BN=256, BK=64, 8 waves (2M x 4N), per-wave 128x64, acc[8][4].
// LDS 128KB: buf{0,1} x (A[2x 128x64] | B[2x 128x64]) bf16, XOR-swizzled
// byte ^= ((row&7)<<4) within each 128B row; gload_lds dest linear, source
// pre-inverse-swizzled (rule #21). vmcnt(2) at phases 4/8 only.

#define BAR() __builtin_amdgcn_s_barrier()
#define VMC2() asm volatile("s_waitcnt vmcnt(2)" ::: "memory")
#define VMC0() asm volatile("s_waitcnt vmcnt(0)" ::: "memory")

// stage half-tile H (0=A0,1=A1,2=B0,3=B1) of K-tile kt into buffer bf
#define STAGE(bf, H, kt) do {                                              \
    const char* _s = pH[H] + (size_t)(kt) * 128;                           \
    AS3 char* _d = (AS3 char*)lds + (bf) * 65536 + (H) * 16384 + wv1024;   \
    __builtin_amdgcn_global_load_lds((const AS1 void*)_s, (AS3 void*)_d,   \
                                     16, 0, 0);                            \
    __builtin_amdgcn_global_load_lds((const AS1 void*)(_s + 524288),       \
                                     (AS3 void*)(_d + 8192), 16, 0, 0);    \
  } while (0)

// load A-quadrant mh (4 mf x 2 ks) from buffer byte-offset BUFB
#define LDAQ(mh, BUFB)                                                     \
  _Pragma("unroll") for (int mi = 0; mi < 4; ++mi)                         \
  _Pragma("unroll") for (int ks = 0; ks < 2; ++ks)                         \
    a[mi][ks] = *(const bf16x8*)(ldsc + (BUFB) + abase +                   \
                                 ((mh) * 4 + mi) * 2048 + (cs0 ^ (ks << 6)));

// load B-halfquad nh (2 nf x 2 ks)
#define LDBQ(nh, B_, BUFB)                                                 \
  _Pragma("unroll") for (int nj = 0; nj < 2; ++nj)                         \
  _Pragma("unroll") for (int ks = 0; ks < 2; ++ks)                         \
    B_[nj][ks] = *(const bf16x8*)(ldsc + (BUFB) + bbase +                  \
                                  ((nh) * 2 + nj) * 2048 + (cs0 ^ (ks << 6)));

// 16 MFMA: quadrant (mh,nh)
#define QMFMA(mh, nh, B_) do {                                             \
    __builtin_amdgcn_s_setprio(1);                                         \
    _Pragma("unroll") for (int mi = 0; mi < 4; ++mi)                       \
    _Pragma("unroll") for (int nj = 0; nj < 2; ++nj)                       \
    _Pragma("unroll") for (int ks = 0; ks < 2; ++ks)                       \
      acc[(mh) * 4 + mi][(nh) * 2 + nj] =                                  \
          __builtin_amdgcn_mfma_f32_16x16x32_bf16(                         \
              a[mi][ks], B_[nj][ks], acc[(mh) * 4 + mi][(nh) * 2 + nj],    \
              0, 0, 0);                                                    \
    __builtin_amdgcn_s_setprio(0);                                         \
  } while (0)

__global__ __launch_bounds__(512, 2) void k_gemm(
    const unsigned short* __restrict__ xb, const unsigned short* __restrict__ wq,
    const float* __restrict__ se, float* __restrict__ out) {
  __shared__ alignas(16) char lds[131072];
  const int t = threadIdx.x;
  const int lane = t & 63;
  const int wave = t >> 6;
  const int wm = wave >> 2, wn = wave & 3;

  // XCD chunking: XCD x gets bm in [x*8, x*8+8), all 16 bn; bm-fast order
  // so the 32 concurrent blocks per XCD form an 8bm x 4bn square.
  const int bid = blockIdx.x;
  const int bm = (bid & 7) * 8 + ((bid >> 3) & 7);  // 0..63
  const int bn = bid >> 6;                          // 0..15
  const size_t arow0 = (size_t)bm * 256;
  const size_t bcol0 = (size_t)bn * 256;

  // ---- staging source (inverse-swizzled global address) ----
  const int d0 = t * 16;                 // linear dest byte within half-tile
  const int r0 = d0 >> 7;                // dest row 0..63 (j=1 adds 64)
  const int c0s = (d0 & 127) ^ ((r0 & 7) << 4);
  const char* gA = (const char*)xb + arow0 * 8192;
  const char* gB = (const char*)wq + bcol0 * 8192;
  const char* pH[4] = {gA + (size_t)r0 * 8192 + c0s,
                       gA + (size_t)(128 + r0) * 8192 + c0s,
                       gB + (size_t)r0 * 8192 + c0s,
                       gB + (size_t)(128 + r0) * 8192 + c0s};
  const int wv1024 = wave * 1024;

  // ---- fragment read addressing (swizzled) ----
  const int la = lane & 15, kg = lane >> 4;
  const int cs0 = (kg << 4) ^ ((lane & 7) << 4);
  const int abase = wm * 16384 + la * 128;
  const int bbase = 32768 + (wn >> 1) * 16384 + ((wn & 1) * 64 + la) * 128;
  const char* ldsc = (const char*)lds;

  f32x4 acc[8][4] = {};
  bf16x8 a[4][2], bl[2][2], bh[2][2];

  // prologue: tile0 fully + tile1 half A0; land tile0, keep tile1A0 in flight
  STAGE(0, 0, 0); STAGE(0, 1, 0); STAGE(0, 2, 0); STAGE(0, 3, 0);
  STAGE(1, 0, 1);
  VMC2();
  BAR();

  for (int i = 0; i < 31; ++i) {
    const int t2 = 2 * i;
    // P1: read buf0 A[mh0]+B[nh0]; stage (t+1).A1 -> buf1
    LDAQ(0, 0); LDBQ(0, bl, 0);
    STAGE(1, 1, t2 + 1);
    BAR(); QMFMA(0, 0, bl); BAR();
    // P2: read B[nh1]; stage (t+1).B0
    LDBQ(1, bh, 0);
    STAGE(1, 2, t2 + 1);
    BAR(); QMFMA(0, 1, bh); BAR();
    // P3: read A[mh1]; stage (t+1).B1
    LDAQ(1, 0);
    STAGE(1, 3, t2 + 1);
    BAR(); QMFMA(1, 0, bl); BAR();
    // P4: stage (t+2).A0 -> buf0; ensure tile t+1 landed (leave 1 half in flight)
    STAGE(0, 0, t2 + 2);
    VMC2();
    BAR(); QMFMA(1, 1, bh); BAR();
    // P5: read buf1 A[mh0]+B[nh0]; stage (t+2).A1
    LDAQ(0, 65536); LDBQ(0, bl, 65536);
    STAGE(0, 1, t2 + 2);
    BAR(); QMFMA(0, 0, bl); BAR();
    // P6: stage (t+2).B0
    LDBQ(1, bh, 65536);
    STAGE(0, 2, t2 + 2);
    BAR(); QMFMA(0, 1, bh); BAR();
    // P7: stage (t+2).B1
    LDAQ(1, 65536);
    STAGE(0, 3, t2 + 2);
    BAR(); QMFMA(1, 0, bl); BAR();
    // P8: stage (t+3).A0 -> buf1; ensure tile t+2 landed
    STAGE(1, 0, t2 + 3);
    VMC2();
    BAR(); QMFMA(1, 1, bh); BAR();
  }

  // peel: tiles 62 (buf0) / 63 (buf1); finish staging 63.{A1,B0,B1}
  LDAQ(0, 0); LDBQ(0, bl, 0);
  STAGE(1, 1, 63);
  BAR(); QMFMA(0, 0, bl); BAR();
  LDBQ(1, bh, 0);
  STAGE(1, 2, 63);
  BAR(); QMFMA(0, 1, bh); BAR();
  LDAQ(1, 0);
  STAGE(1, 3, 63);
  BAR(); QMFMA(1, 0, bl); BAR();
  VMC0();
  BAR(); QMFMA(1, 1, bh); BAR();
  // tile 63: no more staging -> plain compute
  LDAQ(0, 65536); LDBQ(0, bl, 65536);
  QMFMA(0, 0, bl);
  LDBQ(1, bh, 65536);
  QMFMA(0, 1, bh);
  LDAQ(1, 65536);
  QMFMA(1, 0, bl);
  QMFMA(1, 1, bh);

  // epilogue: C/D layout col = lane&15, row = (lane>>4)*4 + j  [m89/m91]
  const int rj = kg * 4;
#pragma unroll
  for (int nf = 0; nf < 4; ++nf) {
    const size_t col = bcol0 + wn * 64 + nf * 16 + la;
    const float sev = se[col];
#pragma unroll
    for (int mf = 0; mf < 8; ++mf) {
      const size_t row = arow0 + wm * 128 + mf * 16 + rj;
#pragma unroll
      for (int j = 0; j < 4; ++j)
        out[(row + j) * 4096 + col] = acc[mf][nf][j] * sev;
    }
  }
}

extern "C" void kernel_launch(void* const* d_in, const int* in_sizes, int n_in,
                              void* d_out, int out_size, void* d_ws, size_t ws_size,
                              hipStream_t stream) {
  const float* x     = (const float*)d_in[0];
  const float* w     = (const float*)d_in[1];
  const float* scale = (const float*)d_in[3];
  const float* lrA   = (const float*)d_in[4];
  const float* lrB   = (const float*)d_in[5];
  float* out = (float*)d_out;

  char* ws = (char*)d_ws;
  unsigned short* xb  = (unsigned short*)ws;                    // 134217728 B
  unsigned short* wq  = (unsigned short*)(ws + 134217728);      //  33554432 B
  float* partials     = (float*)(ws + 167772160);               //   8388608 B
  float* partial2     = (float*)(ws + 176160768);               //     65536 B
  float* tmp          = (float*)(ws + 176226304);               //        64 B
  float* se           = (float*)(ws + 176226368);               //     16384 B

  k_convert_reduce<<<512, 256, 0, stream>>>(x, xb, partials);
  k_reduce2<<<64, 256, 0, stream>>>(partials, partial2);
  k_tmp<<<16, 256, 0, stream>>>(lrB, partial2, tmp);
  k_scale<<<16, 256, 0, stream>>>(lrA, scale, tmp, se);
  k_quant<<<16384, 256, 0, stream>>>(w, wq);
  k_gemm<<<1024, 512, 0, stream>>>(xb, wq, se, out);
}